// Round 16
// baseline (10699.879 us; speedup 1.0000x reference)
//
#include <hip/hip_runtime.h>
#include <cstdint>

typedef unsigned long long u64;

// B=64 S=1024 D_IN=256 D_HID=512 D_LAT=128, GRU: 128->256->128, out 2
#define TOKENS 65536

// ---------------- ws layout (bytes), all f32 ----------------
#define WS_XL    0ULL
#define WS_HENC  67108864ULL
#define WS_GI0   0ULL
#define WS_XBUF0 201326592ULL                    // u64[64][2][256] = 262144 B
#define WS_XBUF1 (201326592ULL + 262144ULL)      // u64[64][2][128] = 131072 B
#define WS_MUS   (201326592ULL + 393216ULL)
#define WS_MUT   (201326592ULL + 393728ULL)
#define WS_NEED  (201326592ULL + 394240ULL)

// ---------------- LDS layout for k_scan_f (bytes inside extern smem) ----------------
// L1 weights column-major, row-dim padded to 97 (odd) -> b32 reads conflict-free.
#define L_W1I  0           // f32[256][97]  = 99328
#define L_W1H  99328       // f32[128][97]  = 49664
#define L_H0   148992      // f32[256]
#define L_H1   150016      // f32[128]
#define L_G0   150528      // f32[192]
#define L_G1I  151296      // f32[96]
#define L_G1H  151680      // f32[96]
#define L_R1   152064      // f32[4]
#define L_R2   152080      // f32[4]
#define L_R1B  152096      // f32[2]
#define L_R2B  152104      // f32[2]
#define L_SIZE 152128

// ---------------- prep: fold BN into scale/shift ----------------
__global__ void k_prep(const float* __restrict__ bmu, const float* __restrict__ bng,
                       const float* __restrict__ bnb, const float* __restrict__ bnrm,
                       const float* __restrict__ bnrv,
                       float* __restrict__ mus, float* __restrict__ mut)
{
    int j = threadIdx.x;
    if (j < 128) {
        float s = bng[j] / sqrtf(bnrv[j] + 1e-5f);
        mus[j] = s;
        mut[j] = bmu[j] * s + bnb[j] - bnrm[j] * s;
    }
}

// ---------------- xl = log(softplus(x)), f32 ----------------
__global__ void k_xl(const float* __restrict__ x, float* __restrict__ xl, int n4)
{
    int i = blockIdx.x * blockDim.x + threadIdx.x;
    if (i >= n4) return;
    float4 v = ((const float4*)x)[i];
    float4 o;
    o.x = logf(v.x > 20.f ? v.x : log1pf(expf(v.x)));
    o.y = logf(v.y > 20.f ? v.y : log1pf(expf(v.y)));
    o.z = logf(v.z > 20.f ? v.z : log1pf(expf(v.z)));
    o.w = logf(v.w > 20.f ? v.w : log1pf(expf(v.w)));
    ((float4*)xl)[i] = o;
}

// ---------------- f32 tiled GEMM (r12 verbatim): C = epi(acc*s + t) ----------------
template<int EPI, int AZ>
__global__ __launch_bounds__(256) void k_gemm_f32(
    const float* __restrict__ A, const float* __restrict__ W,
    const float* __restrict__ svec, const float* __restrict__ tvec,
    float* __restrict__ C, int N, int K,
    const float* __restrict__ ZMU, const float* __restrict__ ZLV, const float* __restrict__ ZEP)
{
    __shared__ float As[32][132];
    __shared__ float Ws[32][132];
    const int tid = threadIdx.x;
    const int tx = tid & 15, ty = tid >> 4;
    const int m0 = blockIdx.x * 128;
    const int n0 = blockIdx.y * 128;
    float acc[8][8];
#pragma unroll
    for (int i = 0; i < 8; ++i)
#pragma unroll
        for (int j = 0; j < 8; ++j) acc[i][j] = 0.f;

    for (int k0 = 0; k0 < K; k0 += 32) {
#pragma unroll
        for (int it = 0; it < 4; ++it) {
            int id = tid + 256 * it;
            int r = id >> 3, c4 = id & 7;
            float4 av;
            if constexpr (AZ) {
                size_t idx = (size_t)(m0 + r) * K + k0 + c4 * 4;
                float4 m4 = *(const float4*)(ZMU + idx);
                float4 l4 = *(const float4*)(ZLV + idx);
                float4 e4 = *(const float4*)(ZEP + idx);
                av.x = m4.x + e4.x * expf(0.5f * l4.x);
                av.y = m4.y + e4.y * expf(0.5f * l4.y);
                av.z = m4.z + e4.z * expf(0.5f * l4.z);
                av.w = m4.w + e4.w * expf(0.5f * l4.w);
            } else {
                av = *(const float4*)(A + (size_t)(m0 + r) * K + k0 + c4 * 4);
            }
            float4 wv = *(const float4*)(W + (size_t)(n0 + r) * K + k0 + c4 * 4);
            As[c4*4+0][r] = av.x; As[c4*4+1][r] = av.y; As[c4*4+2][r] = av.z; As[c4*4+3][r] = av.w;
            Ws[c4*4+0][r] = wv.x; Ws[c4*4+1][r] = wv.y; Ws[c4*4+2][r] = wv.z; Ws[c4*4+3][r] = wv.w;
        }
        __syncthreads();
#pragma unroll
        for (int k = 0; k < 32; ++k) {
            float4 a0 = *(const float4*)&As[k][ty*8];
            float4 a1 = *(const float4*)&As[k][ty*8+4];
            float4 w0 = *(const float4*)&Ws[k][tx*8];
            float4 w1 = *(const float4*)&Ws[k][tx*8+4];
            float ar[8] = {a0.x,a0.y,a0.z,a0.w,a1.x,a1.y,a1.z,a1.w};
            float wr[8] = {w0.x,w0.y,w0.z,w0.w,w1.x,w1.y,w1.z,w1.w};
#pragma unroll
            for (int i = 0; i < 8; ++i)
#pragma unroll
                for (int j = 0; j < 8; ++j) acc[i][j] += ar[i] * wr[j];
        }
        __syncthreads();
    }
#pragma unroll
    for (int i = 0; i < 8; ++i) {
        size_t m = (size_t)m0 + ty*8 + i;
#pragma unroll
        for (int j4 = 0; j4 < 2; ++j4) {
            float o[4];
#pragma unroll
            for (int j = 0; j < 4; ++j) {
                int col = n0 + tx*8 + j4*4 + j;
                float v = acc[i][j4*4+j];
                if (svec) v *= svec[col];
                v += tvec[col];
                if constexpr (EPI == 1) v = fmaxf(v, 0.f);
                if constexpr (EPI == 2) v = fminf(fmaxf(v, -10.f), 10.f);
                if constexpr (EPI == 3) v = expf(v);
                o[j] = v;
            }
            *(float4*)(C + m * N + n0 + tx*8 + j4*4) = *(float4*)o;
        }
    }
}

// ============ parity-tagged exchange (r13 verbatim, verified bit-exact) ============
__device__ __forceinline__ void tstore(u64* p, float v, unsigned tag) {
    u64 w = ((u64)tag << 32) | (u64)__builtin_bit_cast(unsigned, v);
    __hip_atomic_store(p, w, __ATOMIC_RELAXED, __HIP_MEMORY_SCOPE_AGENT);
}
__device__ __forceinline__ float tpoll(const u64* p, unsigned tag) {
    u64 w = 0; int guard = 0;
    do {
        w = __hip_atomic_load(p, __ATOMIC_RELAXED, __HIP_MEMORY_SCOPE_AGENT);
        if ((unsigned)(w >> 32) == tag) break;
        __builtin_amdgcn_s_sleep(1);
    } while (++guard < (1 << 17));
    return __builtin_bit_cast(float, (unsigned)w);
}
__device__ __forceinline__ void rbar() {
    asm volatile("s_waitcnt lgkmcnt(0)" ::: "memory");
    __builtin_amdgcn_s_barrier();
}

// ---------------- fused scan: 256 blocks (4/batch), 256 threads, 152KB LDS ----------------
// Iter u: threads 0-191 = L0 dot for t=u (VGPR-resident Whh0 quarter, frozen r13 code)
//         THEN (u>0) one L1 row each for t=u-1 from LDS (col-major, conflict-free b32).
//         Wave 3 = gi0[u] loads. One exchange round per iter (L0 hn[256] + L1 hn[128]);
//         dual-LN rides shared barrier slots (frozen r13). No h0s stream, no weight streaming.
__global__ __launch_bounds__(256)
__attribute__((amdgpu_waves_per_eu(1, 1)))
void k_scan_f(const float* gi0, const float* wh0, const float* bhh0,
              const float* wi1, const float* wh1,
              const float* bih1, const float* bhh1,
              const float* lg0, const float* lb0,
              const float* lg1, const float* lb1,
              const float* fcW, const float* fcb,
              float* vout, u64* xbuf0, u64* xbuf1)
{
    extern __shared__ char smem[];
    float* W1I  = (float*)(smem + L_W1I);
    float* W1H  = (float*)(smem + L_W1H);
    float* s_h0 = (float*)(smem + L_H0);
    float* s_h1 = (float*)(smem + L_H1);
    float* s_g0 = (float*)(smem + L_G0);
    float* s_g1i= (float*)(smem + L_G1I);
    float* s_g1h= (float*)(smem + L_G1H);
    float* s_r1 = (float*)(smem + L_R1);
    float* s_r2 = (float*)(smem + L_R2);
    float* s_r1b= (float*)(smem + L_R1B);
    float* s_r2b= (float*)(smem + L_R2B);

    const int xcd  = blockIdx.x & 7;
    const int slot = blockIdx.x >> 3;
    const int b    = xcd * 8 + (slot >> 2);
    const int q    = slot & 3;
    const int tid  = threadIdx.x;
    const int lane = tid & 63;
    const int wvi  = tid >> 6;

    // L0 resident weights (frozen r13 layout)
    int row = 0;
    if (tid < 192)
        row = (tid < 64) ? (64*q + tid)
            : (tid < 128) ? (256 + 64*q + (tid-64))
                          : (512 + 64*q + (tid-128));
    float4 wr[64];
    float bA = 0.f;
    if (tid < 192) {
        const float4* p = (const float4*)(wh0 + (size_t)row * 256);
#pragma unroll
        for (int i = 0; i < 64; ++i) wr[i] = p[i];
        bA = bhh0[row];
    }
    // L1 weights -> LDS column-major (coalesced global reads, one-time)
    for (int idx = tid; idx < 24576; idx += 256) {
        int rho = idx >> 8, w = idx & 255;
        int grow = 128 * (rho >> 5) + 32 * q + (rho & 31);
        W1I[w * 97 + rho] = wi1[(size_t)grow * 256 + w];
    }
    for (int idx = tid; idx < 12288; idx += 256) {
        int rho = idx >> 7, w = idx & 127;
        int grow = 128 * (rho >> 5) + 32 * q + (rho & 31);
        W1H[w * 97 + rho] = wh1[(size_t)grow * 128 + w];
    }
    float bB = 0.f;
    if (tid < 96)       bB = bih1[128 * (tid >> 5) + 32 * q + (tid & 31)];
    else if (tid < 192) { int r2 = tid - 96; bB = bhh1[128 * (r2 >> 5) + 32 * q + (r2 & 31)]; }

    const float gv0 = lg0[tid], bv0 = lb0[tid];
    float gv1 = 0.f, bv1 = 0.f;
    if (tid < 128) { gv1 = lg1[tid]; bv1 = lb1[tid]; s_h1[tid] = 0.f; }
    s_h0[tid] = 0.f;
    __syncthreads();

    const float* gbase = gi0 + (size_t)b * 1024 * 768;
    u64* xb0 = xbuf0 + (size_t)b * 512;   // [2][256]
    u64* xb1 = xbuf1 + (size_t)b * 256;   // [2][128]

    for (int u = 0; u < 1024; ++u) {
        const int par = u & 1;
        float gr = 0.f, gz = 0.f, gn = 0.f;
        if (tid < 192) {
            // frozen L0 dot (r13)
            {
                float a0 = bA, a1 = 0.f, a2 = 0.f, a3 = 0.f;
                const float4* H = (const float4*)s_h0;
#pragma unroll
                for (int i = 0; i < 64; ++i) {
                    float4 h4 = H[i];
                    a0 += wr[i].x * h4.x; a1 += wr[i].y * h4.y;
                    a2 += wr[i].z * h4.z; a3 += wr[i].w * h4.w;
                }
                s_g0[tid] = (a0 + a1) + (a2 + a3);
            }
            // L1 dot for t=u-1, one row per thread, LDS col-major (FP order = r13)
            if (u > 0) {
                if (tid < 96) {
                    float a0 = bB, a1 = 0.f, a2 = 0.f, a3 = 0.f;
                    const float4* H0 = (const float4*)s_h0;   // h0[u-1]
#pragma unroll 8
                    for (int i = 0; i < 64; ++i) {
                        float4 h4 = H0[i];
                        float wx = W1I[(4*i+0)*97 + tid];
                        float wy = W1I[(4*i+1)*97 + tid];
                        float wz = W1I[(4*i+2)*97 + tid];
                        float ww = W1I[(4*i+3)*97 + tid];
                        a0 += wx*h4.x; a1 += wy*h4.y; a2 += wz*h4.z; a3 += ww*h4.w;
                    }
                    s_g1i[tid] = (a0 + a1) + (a2 + a3);
                } else {
                    int rho = tid - 96;
                    float a0 = bB, a1 = 0.f, a2 = 0.f, a3 = 0.f;
                    const float4* H1 = (const float4*)s_h1;   // h1[u-2]
#pragma unroll 8
                    for (int i = 0; i < 32; ++i) {
                        float4 h4 = H1[i];
                        float wx = W1H[(4*i+0)*97 + rho];
                        float wy = W1H[(4*i+1)*97 + rho];
                        float wz = W1H[(4*i+2)*97 + rho];
                        float ww = W1H[(4*i+3)*97 + rho];
                        a0 += wx*h4.x; a1 += wy*h4.y; a2 += wz*h4.z; a3 += ww*h4.w;
                    }
                    s_g1h[rho] = (a0 + a1) + (a2 + a3);
                }
            }
        } else {
            const float* gt = gbase + (size_t)u * 768;
            int uu = 64*q + lane;
            gr = gt[uu]; gz = gt[256 + uu]; gn = gt[512 + uu];
        }
        rbar();                                           // B1 (lgkm only)
        if (tid >= 192) {
            // frozen L0 gates (r13)
            int g = lane;
            int uu = 64*q + g;
            float r  = 1.f / (1.f + expf(-(gr + s_g0[g])));
            float zg = 1.f / (1.f + expf(-(gz + s_g0[64 + g])));
            float nn = tanhf(gn + r * s_g0[128 + g]);
            float hn = (1.f - zg) * nn + zg * s_h0[uu];
            tstore(&xb0[par * 256 + uu], hn, (unsigned)(u + 1));
        } else if (tid >= 128 && tid < 160 && u > 0) {
            // frozen L1 gates (r13)
            int g = tid - 128;
            int uuu = 32*q + g;
            float r  = 1.f / (1.f + expf(-(s_g1i[g]      + s_g1h[g])));
            float zg = 1.f / (1.f + expf(-(s_g1i[32 + g] + s_g1h[32 + g])));
            float nn = tanhf(s_g1i[64 + g] + r * s_g1h[64 + g]);
            float hn = (1.f - zg) * nn + zg * s_h1[uuu];
            tstore(&xb1[par * 128 + uuu], hn, (unsigned)(u + 1));
        }
        // distributed poll (no barrier)
        float hn0 = tpoll(&xb0[par * 256 + tid], (unsigned)(u + 1));
        float hn1 = 0.f;
        if (tid < 128 && u > 0) hn1 = tpoll(&xb1[par * 128 + tid], (unsigned)(u + 1));
        // dual-LN: LN1 rides LN0's barrier slots (frozen r13)
        {
            float sum0 = hn0;
#pragma unroll
            for (int o = 32; o > 0; o >>= 1) sum0 += __shfl_xor(sum0, o);
            if (lane == 0) s_r1[wvi] = sum0;
        }
        if (tid < 128 && u > 0) {
            float sum1 = hn1;
#pragma unroll
            for (int o = 32; o > 0; o >>= 1) sum1 += __shfl_xor(sum1, o);
            if (lane == 0) s_r1b[wvi] = sum1;
        }
        rbar();                                           // Bmean
        float m0 = (s_r1[0] + s_r1[1] + s_r1[2] + s_r1[3]) * (1.f / 256.f);
        float d0 = hn0 - m0;
        {
            float ss0 = d0 * d0;
#pragma unroll
            for (int o = 32; o > 0; o >>= 1) ss0 += __shfl_xor(ss0, o);
            if (lane == 0) s_r2[wvi] = ss0;
        }
        float d1 = 0.f;
        if (tid < 128 && u > 0) {
            float m1 = (s_r1b[0] + s_r1b[1]) * (1.f / 128.f);
            d1 = hn1 - m1;
            float ss1 = d1 * d1;
#pragma unroll
            for (int o = 32; o > 0; o >>= 1) ss1 += __shfl_xor(ss1, o);
            if (lane == 0) s_r2b[wvi] = ss1;
        }
        rbar();                                           // Bvar
        float va0 = (s_r2[0] + s_r2[1] + s_r2[2] + s_r2[3]) * (1.f / 256.f);
        float rs0 = 1.f / sqrtf(va0 + 1e-5f);
        s_h0[tid] = d0 * rs0 * gv0 + bv0;
        if (tid < 128 && u > 0) {
            float va1 = (s_r2b[0] + s_r2b[1]) * (1.f / 128.f);
            float rs1 = 1.f / sqrtf(va1 + 1e-5f);
            s_h1[tid] = d1 * rs1 * gv1 + bv1;
        }
        rbar();                                           // B4
    }
    // ---- epilogue: L1 for t=1023 (s_h0=h0[1023], s_h1=h1[1022]); tag 1025, slot 0 ----
    if (tid < 96) {
        float a0 = bB, a1 = 0.f, a2 = 0.f, a3 = 0.f;
        const float4* H0 = (const float4*)s_h0;
#pragma unroll 8
        for (int i = 0; i < 64; ++i) {
            float4 h4 = H0[i];
            float wx = W1I[(4*i+0)*97 + tid];
            float wy = W1I[(4*i+1)*97 + tid];
            float wz = W1I[(4*i+2)*97 + tid];
            float ww = W1I[(4*i+3)*97 + tid];
            a0 += wx*h4.x; a1 += wy*h4.y; a2 += wz*h4.z; a3 += ww*h4.w;
        }
        s_g1i[tid] = (a0 + a1) + (a2 + a3);
    } else if (tid < 192) {
        int rho = tid - 96;
        float a0 = bB, a1 = 0.f, a2 = 0.f, a3 = 0.f;
        const float4* H1 = (const float4*)s_h1;
#pragma unroll 8
        for (int i = 0; i < 32; ++i) {
            float4 h4 = H1[i];
            float wx = W1H[(4*i+0)*97 + rho];
            float wy = W1H[(4*i+1)*97 + rho];
            float wz = W1H[(4*i+2)*97 + rho];
            float ww = W1H[(4*i+3)*97 + rho];
            a0 += wx*h4.x; a1 += wy*h4.y; a2 += wz*h4.z; a3 += ww*h4.w;
        }
        s_g1h[rho] = (a0 + a1) + (a2 + a3);
    }
    rbar();
    if (tid >= 128 && tid < 160) {
        int g = tid - 128;
        int uuu = 32*q + g;
        float r  = 1.f / (1.f + expf(-(s_g1i[g]      + s_g1h[g])));
        float zg = 1.f / (1.f + expf(-(s_g1i[32 + g] + s_g1h[32 + g])));
        float nn = tanhf(s_g1i[64 + g] + r * s_g1h[64 + g]);
        float hn = (1.f - zg) * nn + zg * s_h1[uuu];
        tstore(&xb1[uuu], hn, 1025u);
    }
    float hn1 = 0.f, d1 = 0.f;
    if (tid < 128) {
        hn1 = tpoll(&xb1[tid], 1025u);
        float sum1 = hn1;
#pragma unroll
        for (int o = 32; o > 0; o >>= 1) sum1 += __shfl_xor(sum1, o);
        if (lane == 0) s_r1b[wvi] = sum1;
    }
    rbar();
    if (tid < 128) {
        float m1 = (s_r1b[0] + s_r1b[1]) * (1.f / 128.f);
        d1 = hn1 - m1;
        float ss1 = d1 * d1;
#pragma unroll
        for (int o = 32; o > 0; o >>= 1) ss1 += __shfl_xor(ss1, o);
        if (lane == 0) s_r2b[wvi] = ss1;
    }
    rbar();
    float p0 = 0.f, p1 = 0.f;
    if (tid < 128) {
        float va1 = (s_r2b[0] + s_r2b[1]) * (1.f / 128.f);
        float rs1 = 1.f / sqrtf(va1 + 1e-5f);
        float hold = d1 * rs1 * gv1 + bv1;
        p0 = fcW[tid] * hold;
        p1 = fcW[128 + tid] * hold;
#pragma unroll
        for (int o = 32; o > 0; o >>= 1) { p0 += __shfl_xor(p0, o); p1 += __shfl_xor(p1, o); }
        if (lane == 0) { s_r1[wvi] = p0; s_r2[wvi] = p1; }
    }
    __syncthreads();
    if (tid == 0 && q == 0) {
        vout[b * 2 + 0] = s_r1[0] + s_r1[1] + fcb[0];
        vout[b * 2 + 1] = s_r2[0] + s_r2[1] + fcb[1];
    }
}

// ---------------- launcher ----------------
extern "C" void kernel_launch(void* const* d_in, const int* in_sizes, int n_in,
                              void* d_out, int out_size, void* d_ws, size_t ws_size,
                              hipStream_t stream)
{
    const float* x     = (const float*)d_in[0];
    const float* eps   = (const float*)d_in[1];
    const float* W1lv  = (const float*)d_in[2];
    const float* b1lv  = (const float*)d_in[3];
    const float* W2lv  = (const float*)d_in[4];
    const float* b2lv  = (const float*)d_in[5];
    const float* Wmu   = (const float*)d_in[6];
    const float* bmu   = (const float*)d_in[7];
    const float* bn_g  = (const float*)d_in[8];
    const float* bn_b  = (const float*)d_in[9];
    const float* bn_rm = (const float*)d_in[10];
    const float* bn_rv = (const float*)d_in[11];
    const float* Wdec  = (const float*)d_in[12];
    const float* bdec  = (const float*)d_in[13];
    const float* Wih0  = (const float*)d_in[14];
    const float* Whh0  = (const float*)d_in[15];
    const float* bih0  = (const float*)d_in[16];
    const float* bhh0  = (const float*)d_in[17];
    const float* Wih1  = (const float*)d_in[18];
    const float* Whh1  = (const float*)d_in[19];
    const float* bih1  = (const float*)d_in[20];
    const float* bhh1  = (const float*)d_in[21];
    const float* ln_g0 = (const float*)d_in[22];
    const float* ln_b0 = (const float*)d_in[23];
    const float* ln_g1 = (const float*)d_in[24];
    const float* ln_b1 = (const float*)d_in[25];
    const float* fc_W  = (const float*)d_in[26];
    const float* fc_b  = (const float*)d_in[27];

    float* out   = (float*)d_out;
    float* v_out = out;                                   // [64,2]
    float* xrec  = out + 128;                             // [64,1024,256]
    float* mu    = out + 128 + 16777216;                  // [64,1024,128]
    float* lv    = out + 128 + 16777216 + 8388608;        // [64,1024,128]

    if (ws_size < WS_NEED) return;  // distinctive failure: outputs stay zero
    char* ws = (char*)d_ws;
    float* XL    = (float*)(ws + WS_XL);
    float* HENC  = (float*)(ws + WS_HENC);
    float* GI0   = (float*)(ws + WS_GI0);    // overlays XL+HENC (dead by then)
    u64*   XBUF0 = (u64*)(ws + WS_XBUF0);
    u64*   XBUF1 = (u64*)(ws + WS_XBUF1);
    float* MUS   = (float*)(ws + WS_MUS);
    float* MUT   = (float*)(ws + WS_MUT);

    k_prep<<<1, 128, 0, stream>>>(bmu, bn_g, bn_b, bn_rm, bn_rv, MUS, MUT);
    k_xl<<<16384, 256, 0, stream>>>(x, XL, 4194304);
    // encoder
    k_gemm_f32<1,0><<<dim3(512, 4), 256, 0, stream>>>(XL,   W1lv, nullptr, b1lv, HENC, 512, 256, nullptr, nullptr, nullptr);
    k_gemm_f32<0,0><<<dim3(512, 1), 256, 0, stream>>>(HENC, W2lv, nullptr, b2lv, lv,   128, 512, nullptr, nullptr, nullptr);
    k_gemm_f32<2,0><<<dim3(512, 1), 256, 0, stream>>>(XL,   Wmu,  MUS,     MUT,  mu,   128, 256, nullptr, nullptr, nullptr);
    // gi0 GEMM with fused reparameterization (XL/HENC dead -> GI0 overlays them)
    k_gemm_f32<0,1><<<dim3(512, 6), 256, 0, stream>>>(nullptr, Wih0, nullptr, bih0, GI0, 768, 128, mu, lv, eps);
    // decoder with fused reparameterization
    k_gemm_f32<3,1><<<dim3(512, 2), 256, 0, stream>>>(nullptr, Wdec, nullptr, bdec, xrec, 256, 128, mu, lv, eps);
    // reset exchange tag buffers (per launch; tag 0 != any step tag)
    hipMemsetAsync(XBUF0, 0, 393216, stream);
    // fused scan: both GRU layers, one tagged sync round per step; 152KB dynamic LDS
    hipFuncSetAttribute((const void*)k_scan_f, hipFuncAttributeMaxDynamicSharedMemorySize, 160 * 1024);
    k_scan_f<<<256, 256, L_SIZE, stream>>>(GI0, Whh0, bhh0, Wih1, Whh1, bih1, bhh1,
                                           ln_g0, ln_b0, ln_g1, ln_b1, fc_W, fc_b,
                                           v_out, XBUF0, XBUF1);
}

// Round 17
// 6889.247 us; speedup vs baseline: 1.5531x; 1.5531x over previous
//
#include <hip/hip_runtime.h>
#include <cstdint>

typedef unsigned long long u64;

// B=64 S=1024 D_IN=256 D_HID=512 D_LAT=128, GRU: 128->256->128, out 2
#define TOKENS 65536

// ---------------- ws layout (bytes), all f32 ----------------
// GI0 (192MB) at [0,192M) during scan0; GI1 (96MB) overlays [0,96M) after scan0.
#define WS_XL    0ULL
#define WS_HENC  67108864ULL
#define WS_GI0   0ULL
#define WS_GI1   0ULL
#define WS_XBUF0 201326592ULL                    // u64[64][256] = 131072 B (scan0 exchange)
#define WS_MUS   (201326592ULL + 196608ULL)
#define WS_MUT   (201326592ULL + 197120ULL)
#define WS_NEED  (201326592ULL + 197632ULL)

// ---------------- prep: fold BN into scale/shift ----------------
__global__ void k_prep(const float* __restrict__ bmu, const float* __restrict__ bng,
                       const float* __restrict__ bnb, const float* __restrict__ bnrm,
                       const float* __restrict__ bnrv,
                       float* __restrict__ mus, float* __restrict__ mut)
{
    int j = threadIdx.x;
    if (j < 128) {
        float s = bng[j] / sqrtf(bnrv[j] + 1e-5f);
        mus[j] = s;
        mut[j] = bmu[j] * s + bnb[j] - bnrm[j] * s;
    }
}

// ---------------- xl = log(softplus(x)), f32 ----------------
__global__ void k_xl(const float* __restrict__ x, float* __restrict__ xl, int n4)
{
    int i = blockIdx.x * blockDim.x + threadIdx.x;
    if (i >= n4) return;
    float4 v = ((const float4*)x)[i];
    float4 o;
    o.x = logf(v.x > 20.f ? v.x : log1pf(expf(v.x)));
    o.y = logf(v.y > 20.f ? v.y : log1pf(expf(v.y)));
    o.z = logf(v.z > 20.f ? v.z : log1pf(expf(v.z)));
    o.w = logf(v.w > 20.f ? v.w : log1pf(expf(v.w)));
    ((float4*)xl)[i] = o;
}

// ---------------- f32 tiled GEMM (r12 verbatim): C = epi(acc*s + t) ----------------
template<int EPI, int AZ>
__global__ __launch_bounds__(256) void k_gemm_f32(
    const float* __restrict__ A, const float* __restrict__ W,
    const float* __restrict__ svec, const float* __restrict__ tvec,
    float* __restrict__ C, int N, int K,
    const float* __restrict__ ZMU, const float* __restrict__ ZLV, const float* __restrict__ ZEP)
{
    __shared__ float As[32][132];
    __shared__ float Ws[32][132];
    const int tid = threadIdx.x;
    const int tx = tid & 15, ty = tid >> 4;
    const int m0 = blockIdx.x * 128;
    const int n0 = blockIdx.y * 128;
    float acc[8][8];
#pragma unroll
    for (int i = 0; i < 8; ++i)
#pragma unroll
        for (int j = 0; j < 8; ++j) acc[i][j] = 0.f;

    for (int k0 = 0; k0 < K; k0 += 32) {
#pragma unroll
        for (int it = 0; it < 4; ++it) {
            int id = tid + 256 * it;
            int r = id >> 3, c4 = id & 7;
            float4 av;
            if constexpr (AZ) {
                size_t idx = (size_t)(m0 + r) * K + k0 + c4 * 4;
                float4 m4 = *(const float4*)(ZMU + idx);
                float4 l4 = *(const float4*)(ZLV + idx);
                float4 e4 = *(const float4*)(ZEP + idx);
                av.x = m4.x + e4.x * expf(0.5f * l4.x);
                av.y = m4.y + e4.y * expf(0.5f * l4.y);
                av.z = m4.z + e4.z * expf(0.5f * l4.z);
                av.w = m4.w + e4.w * expf(0.5f * l4.w);
            } else {
                av = *(const float4*)(A + (size_t)(m0 + r) * K + k0 + c4 * 4);
            }
            float4 wv = *(const float4*)(W + (size_t)(n0 + r) * K + k0 + c4 * 4);
            As[c4*4+0][r] = av.x; As[c4*4+1][r] = av.y; As[c4*4+2][r] = av.z; As[c4*4+3][r] = av.w;
            Ws[c4*4+0][r] = wv.x; Ws[c4*4+1][r] = wv.y; Ws[c4*4+2][r] = wv.z; Ws[c4*4+3][r] = wv.w;
        }
        __syncthreads();
#pragma unroll
        for (int k = 0; k < 32; ++k) {
            float4 a0 = *(const float4*)&As[k][ty*8];
            float4 a1 = *(const float4*)&As[k][ty*8+4];
            float4 w0 = *(const float4*)&Ws[k][tx*8];
            float4 w1 = *(const float4*)&Ws[k][tx*8+4];
            float ar[8] = {a0.x,a0.y,a0.z,a0.w,a1.x,a1.y,a1.z,a1.w};
            float wr[8] = {w0.x,w0.y,w0.z,w0.w,w1.x,w1.y,w1.z,w1.w};
#pragma unroll
            for (int i = 0; i < 8; ++i)
#pragma unroll
                for (int j = 0; j < 8; ++j) acc[i][j] += ar[i] * wr[j];
        }
        __syncthreads();
    }
#pragma unroll
    for (int i = 0; i < 8; ++i) {
        size_t m = (size_t)m0 + ty*8 + i;
#pragma unroll
        for (int j4 = 0; j4 < 2; ++j4) {
            float o[4];
#pragma unroll
            for (int j = 0; j < 4; ++j) {
                int col = n0 + tx*8 + j4*4 + j;
                float v = acc[i][j4*4+j];
                if (svec) v *= svec[col];
                v += tvec[col];
                if constexpr (EPI == 1) v = fmaxf(v, 0.f);
                if constexpr (EPI == 2) v = fminf(fmaxf(v, -10.f), 10.f);
                if constexpr (EPI == 3) v = expf(v);
                o[j] = v;
            }
            *(float4*)(C + m * N + n0 + tx*8 + j4*4) = *(float4*)o;
        }
    }
}

// ============ tagged exchange (r12 verbatim; scan0 only) ============
__device__ __forceinline__ void tstore(u64* p, float v, unsigned tag) {
    u64 w = ((u64)tag << 32) | (u64)__builtin_bit_cast(unsigned, v);
    __hip_atomic_store(p, w, __ATOMIC_RELAXED, __HIP_MEMORY_SCOPE_AGENT);
}
__device__ __forceinline__ float tpoll(const u64* p, unsigned tag) {
    u64 w = 0; int guard = 0;
    do {
        w = __hip_atomic_load(p, __ATOMIC_RELAXED, __HIP_MEMORY_SCOPE_AGENT);
        if ((unsigned)(w >> 32) == tag) break;
        __builtin_amdgcn_s_sleep(1);
    } while (++guard < (1 << 17));
    return __builtin_bit_cast(float, (unsigned)w);
}
__device__ __forceinline__ void rbar() {
    asm volatile("s_waitcnt lgkmcnt(0)" ::: "memory");
    __builtin_amdgcn_s_barrier();
}

// ---------------- scan layer 0 (r12 verbatim): 256 blocks (4/batch), 256 threads ----------------
__global__ __launch_bounds__(256)
__attribute__((amdgpu_waves_per_eu(1, 1)))
void k_scan0(const float* gi0, const float* wh0, const float* bhh0,
             const float* lg0, const float* lb0,
             float* h0s, u64* xbuf)
{
    const int xcd  = blockIdx.x & 7;
    const int slot = blockIdx.x >> 3;       // 0..31
    const int b    = xcd * 8 + (slot >> 2); // 4 blocks of b land on one XCD
    const int q    = slot & 3;
    const int tid = threadIdx.x;
    const int lane = tid & 63;
    const int wvi  = tid >> 6;

    __shared__ float s_h[256];
    __shared__ float s_g[192];
    __shared__ float s_r1[4], s_r2[4];

    int row = 0;
    if (tid < 192)
        row = (tid < 64) ? (64*q + tid)
            : (tid < 128) ? (256 + 64*q + (tid-64))
                          : (512 + 64*q + (tid-128));
    float4 wr[64];
    float bA = 0.f;
    if (tid < 192) {
        const float4* p = (const float4*)(wh0 + (size_t)row * 256);
#pragma unroll
        for (int i = 0; i < 64; ++i) wr[i] = p[i];
        bA = bhh0[row];
    }
    const float gv = lg0[tid], bv = lb0[tid];
    s_h[tid] = 0.f;
    __syncthreads();

    const float* gbase = gi0 + (size_t)b * 1024 * 768;
    float* hb = h0s + (size_t)b * 1024 * 256;
    u64* xb = xbuf + (size_t)b * 256;

    for (int t = 0; t < 1024; ++t) {
        float gr = 0.f, gz = 0.f, gn = 0.f;
        if (tid >= 192) {               // wave 3: gi0 loads stay in flight across rbar
            const float* gt = gbase + (size_t)t * 768;
            int u = 64*q + (tid - 192);
            gr = gt[u]; gz = gt[256 + u]; gn = gt[512 + u];
        } else {
            // frozen round-4 dot: groups ascending, x->a0 y->a1 z->a2 w->a3, (a0+a1)+(a2+a3)
            float a0 = bA, a1 = 0.f, a2 = 0.f, a3 = 0.f;
            const float4* H = (const float4*)s_h;
#pragma unroll
            for (int i = 0; i < 64; ++i) {
                float4 h4 = H[i];
                a0 += wr[i].x * h4.x; a1 += wr[i].y * h4.y;
                a2 += wr[i].z * h4.z; a3 += wr[i].w * h4.w;
            }
            s_g[tid] = (a0 + a1) + (a2 + a3);
        }
        rbar();                                           // B1 (lgkm only)
        if (tid >= 192) {
            int g = tid - 192;
            int u = 64*q + g;
            float r  = 1.f / (1.f + expf(-(gr + s_g[g])));
            float zg = 1.f / (1.f + expf(-(gz + s_g[64 + g])));
            float nn = tanhf(gn + r * s_g[128 + g]);
            float hn = (1.f - zg) * nn + zg * s_h[u];
            tstore(&xb[u], hn, (unsigned)(t + 1));        // publish: data+tag, one atomic
        }
        // distributed sync: each thread polls its own unit (no barrier needed)
        float hn = tpoll(&xb[tid], (unsigned)(t + 1));
        // LN0 replay (frozen round-4 sequence)
        float sum = hn;
#pragma unroll
        for (int o = 32; o > 0; o >>= 1) sum += __shfl_xor(sum, o);
        if (lane == 0) s_r1[wvi] = sum;
        rbar();                                           // Bmean
        float m = (s_r1[0] + s_r1[1] + s_r1[2] + s_r1[3]) * (1.f / 256.f);
        float d = hn - m;
        float ss = d * d;
#pragma unroll
        for (int o = 32; o > 0; o >>= 1) ss += __shfl_xor(ss, o);
        if (lane == 0) s_r2[wvi] = ss;
        rbar();                                           // Bvar
        float va = (s_r2[0] + s_r2[1] + s_r2[2] + s_r2[3]) * (1.f / 256.f);
        float rs = 1.f / sqrtf(va + 1e-5f);
        float hl = d * rs * gv + bv;
        s_h[tid] = hl;
        if (q == 0) hb[(size_t)t * 256 + tid] = hl;       // store floats across B4
        rbar();                                           // B4
    }
}

// ---------------- gi1 hoist GEMM: gi1[token][row] = bih1[row] + Wih1[row,:] . h0[token] ----------------
// FROZEN inner loop (byte-copied from r12 scan1's ih dot) -> bit-exact gi1 values.
// grid (256 token-tiles, 2 row-groups); 256 threads: 192 dot (row resident in regs), 64 stagers.
__global__ __launch_bounds__(256)
__attribute__((amdgpu_waves_per_eu(1, 1)))
void k_gi1(const float* h0s, const float* wi1, const float* bih1, float* gi1)
{
    const int bx = blockIdx.x;
    const int by = blockIdx.y;
    const int tid = threadIdx.x;
    __shared__ float s_x[2][4][256];

    float4 wr[64];
    float bB = 0.f;
    const int row = by * 192 + tid;
    if (tid < 192) {
        const float4* p = (const float4*)(wi1 + (size_t)row * 256);
#pragma unroll
        for (int i = 0; i < 64; ++i) wr[i] = p[i];
        bB = bih1[row];
    }
    const float4* xb4 = (const float4*)(h0s + (size_t)bx * 256 * 256);
    if (tid >= 192) {
        int s = tid - 192;
#pragma unroll
        for (int j = 0; j < 4; ++j)
            ((float4*)s_x[0][j])[s] = xb4[(size_t)j * 64 + s];
    }
    __syncthreads();
    for (int r = 0; r < 64; ++r) {
        const int cur = r & 1;
        float4 pf[4];
        const bool stg = (tid >= 192) && (r + 1 < 64);
        if (stg) {
            int s = tid - 192;
#pragma unroll
            for (int j = 0; j < 4; ++j)
                pf[j] = xb4[(size_t)((r + 1) * 4 + j) * 64 + s];
        }
        if (tid < 192) {
#pragma unroll 1
            for (int j = 0; j < 4; ++j) {
                float a0 = bB, a1 = 0.f, a2 = 0.f, a3 = 0.f;
                const float4* X = (const float4*)s_x[cur][j];
#pragma unroll
                for (int i = 0; i < 64; ++i) {
                    float4 h4 = X[i];
                    a0 += wr[i].x * h4.x; a1 += wr[i].y * h4.y;
                    a2 += wr[i].z * h4.z; a3 += wr[i].w * h4.w;
                }
                gi1[(size_t)(bx * 256 + r * 4 + j) * 384 + row] = (a0 + a1) + (a2 + a3);
            }
        } else if (stg) {
            int s = tid - 192;
#pragma unroll
            for (int j = 0; j < 4; ++j)
                ((float4*)s_x[cur ^ 1][j])[s] = pf[j];
        }
        __syncthreads();
    }
}

// ---------------- scan layer 1 (NEW): 64 blocks (1/batch), 512 threads, LDS-only sync ----------------
// ih part hoisted to k_gi1 -> only Whh1 (384 rows x 128) recurrent: fully resident
// (tid<384, 32 float4 = 128 regs, fits 2-waves/SIMD 256-reg cap). NO cross-block exchange.
// tid>=384: gi1 prefetchers (depth-2, LDS double buffer). All FP sequences frozen (r12).
__global__ __launch_bounds__(512)
__attribute__((amdgpu_waves_per_eu(1, 2)))
void k_scan1(const float* gi1, const float* wh1,
             const float* bhh1, const float* lg1, const float* lb1,
             const float* fcW, const float* fcb, float* vout)
{
    const int b   = blockIdx.x;
    const int tid = threadIdx.x;
    const int lane = tid & 63;
    const int wvi  = tid >> 6;

    __shared__ float s_h[128];
    __shared__ float s_g[384];
    __shared__ float s_gi[2][384];
    __shared__ float s_r1[2], s_r2[2];

    float4 wr[32];
    float bB = 0.f;
    if (tid < 384) {
        const float4* p = (const float4*)(wh1 + (size_t)tid * 128);
#pragma unroll
        for (int i = 0; i < 32; ++i) wr[i] = p[i];
        bB = bhh1[tid];
    }
    float gv = 0.f, bv = 0.f;
    if (tid < 128) { gv = lg1[tid]; bv = lb1[tid]; s_h[tid] = 0.f; }

    const float* gb = gi1 + (size_t)b * 1024 * 384;
    // prologue: gi1[0] -> s_gi[0]; gi1[1] -> regs (pipeline depth 2)
    float p_r = 0.f, p_z = 0.f, p_n = 0.f;
    if (tid >= 384) {
        int u = tid - 384;
        s_gi[0][u] = gb[u]; s_gi[0][128 + u] = gb[128 + u]; s_gi[0][256 + u] = gb[256 + u];
        const float* g1 = gb + 384;
        p_r = g1[u]; p_z = g1[128 + u]; p_n = g1[256 + u];
    }
    __syncthreads();

    for (int t = 0; t < 1024; ++t) {
        const int cur = t & 1;
        float f_r = 0.f, f_z = 0.f, f_n = 0.f;
        if (tid >= 384 && t + 2 < 1024) {                 // issue gi1[t+2]
            const float* gt = gb + (size_t)(t + 2) * 384;
            int u = tid - 384;
            f_r = gt[u]; f_z = gt[128 + u]; f_n = gt[256 + u];
        }
        if (tid < 384) {
            // frozen r12 hh dot
            float a0 = bB, a1 = 0.f, a2 = 0.f, a3 = 0.f;
            const float4* Hh = (const float4*)s_h;
#pragma unroll
            for (int i = 0; i < 32; ++i) {
                float4 h4 = Hh[i];
                a0 += wr[i].x * h4.x; a1 += wr[i].y * h4.y;
                a2 += wr[i].z * h4.z; a3 += wr[i].w * h4.w;
            }
            s_g[tid] = (a0 + a1) + (a2 + a3);
        }
        rbar();                                           // B1 (lgkm only)
        float hn = 0.f, d = 0.f;
        if (tid < 128) {
            // frozen r12 gates: ih (hoisted) + hh, same addition order
            float r  = 1.f / (1.f + expf(-(s_gi[cur][tid]       + s_g[tid])));
            float zg = 1.f / (1.f + expf(-(s_gi[cur][128 + tid] + s_g[128 + tid])));
            float nn = tanhf(s_gi[cur][256 + tid] + r * s_g[256 + tid]);
            hn = (1.f - zg) * nn + zg * s_h[tid];
            float sum = hn;
#pragma unroll
            for (int o = 32; o > 0; o >>= 1) sum += __shfl_xor(sum, o);
            if (lane == 0) s_r1[wvi] = sum;
        } else if (tid >= 384 && t + 1 < 1024) {          // write staged gi1[t+1]
            int u = tid - 384;
            s_gi[cur ^ 1][u] = p_r; s_gi[cur ^ 1][128 + u] = p_z; s_gi[cur ^ 1][256 + u] = p_n;
        }
        rbar();                                           // Bmean
        if (tid < 128) {
            float m = (s_r1[0] + s_r1[1]) * (1.f / 128.f);
            d = hn - m;
            float ss = d * d;
#pragma unroll
            for (int o = 32; o > 0; o >>= 1) ss += __shfl_xor(ss, o);
            if (lane == 0) s_r2[wvi] = ss;
        }
        rbar();                                           // Bvar
        if (tid < 128) {
            float va = (s_r2[0] + s_r2[1]) * (1.f / 128.f);
            float rs = 1.f / sqrtf(va + 1e-5f);
            s_h[tid] = d * rs * gv + bv;
        }
        rbar();                                           // B4
        p_r = f_r; p_z = f_z; p_n = f_n;
    }
    // ---- fc head (frozen r12) ----
    float p0 = 0.f, p1 = 0.f;
    if (tid < 128) {
        float hold = s_h[tid];
        p0 = fcW[tid] * hold;
        p1 = fcW[128 + tid] * hold;
#pragma unroll
        for (int o = 32; o > 0; o >>= 1) { p0 += __shfl_xor(p0, o); p1 += __shfl_xor(p1, o); }
        if (lane == 0) { s_r1[wvi] = p0; s_r2[wvi] = p1; }
    }
    __syncthreads();
    if (tid == 0) {
        vout[b * 2 + 0] = s_r1[0] + s_r1[1] + fcb[0];
        vout[b * 2 + 1] = s_r2[0] + s_r2[1] + fcb[1];
    }
}

// ---------------- launcher ----------------
extern "C" void kernel_launch(void* const* d_in, const int* in_sizes, int n_in,
                              void* d_out, int out_size, void* d_ws, size_t ws_size,
                              hipStream_t stream)
{
    const float* x     = (const float*)d_in[0];
    const float* eps   = (const float*)d_in[1];
    const float* W1lv  = (const float*)d_in[2];
    const float* b1lv  = (const float*)d_in[3];
    const float* W2lv  = (const float*)d_in[4];
    const float* b2lv  = (const float*)d_in[5];
    const float* Wmu   = (const float*)d_in[6];
    const float* bmu   = (const float*)d_in[7];
    const float* bn_g  = (const float*)d_in[8];
    const float* bn_b  = (const float*)d_in[9];
    const float* bn_rm = (const float*)d_in[10];
    const float* bn_rv = (const float*)d_in[11];
    const float* Wdec  = (const float*)d_in[12];
    const float* bdec  = (const float*)d_in[13];
    const float* Wih0  = (const float*)d_in[14];
    const float* Whh0  = (const float*)d_in[15];
    const float* bih0  = (const float*)d_in[16];
    const float* bhh0  = (const float*)d_in[17];
    const float* Wih1  = (const float*)d_in[18];
    const float* Whh1  = (const float*)d_in[19];
    const float* bih1  = (const float*)d_in[20];
    const float* bhh1  = (const float*)d_in[21];
    const float* ln_g0 = (const float*)d_in[22];
    const float* ln_b0 = (const float*)d_in[23];
    const float* ln_g1 = (const float*)d_in[24];
    const float* ln_b1 = (const float*)d_in[25];
    const float* fc_W  = (const float*)d_in[26];
    const float* fc_b  = (const float*)d_in[27];

    float* out   = (float*)d_out;
    float* v_out = out;                                   // [64,2]
    float* xrec  = out + 128;                             // [64,1024,256]
    float* mu    = out + 128 + 16777216;                  // [64,1024,128]
    float* lv    = out + 128 + 16777216 + 8388608;        // [64,1024,128]
    float* H0S   = xrec;  // h0 stream parked in xrec; decoder overwrites after k_gi1

    if (ws_size < WS_NEED) return;  // distinctive failure: outputs stay zero
    char* ws = (char*)d_ws;
    float* XL    = (float*)(ws + WS_XL);
    float* HENC  = (float*)(ws + WS_HENC);
    float* GI0   = (float*)(ws + WS_GI0);    // overlays XL+HENC (dead by then)
    float* GI1   = (float*)(ws + WS_GI1);    // overlays GI0 (dead after scan0)
    u64*   XBUF0 = (u64*)(ws + WS_XBUF0);
    float* MUS   = (float*)(ws + WS_MUS);
    float* MUT   = (float*)(ws + WS_MUT);

    k_prep<<<1, 128, 0, stream>>>(bmu, bn_g, bn_b, bn_rm, bn_rv, MUS, MUT);
    k_xl<<<16384, 256, 0, stream>>>(x, XL, 4194304);
    // encoder
    k_gemm_f32<1,0><<<dim3(512, 4), 256, 0, stream>>>(XL,   W1lv, nullptr, b1lv, HENC, 512, 256, nullptr, nullptr, nullptr);
    k_gemm_f32<0,0><<<dim3(512, 1), 256, 0, stream>>>(HENC, W2lv, nullptr, b2lv, lv,   128, 512, nullptr, nullptr, nullptr);
    k_gemm_f32<2,0><<<dim3(512, 1), 256, 0, stream>>>(XL,   Wmu,  MUS,     MUT,  mu,   128, 256, nullptr, nullptr, nullptr);
    // gi0 GEMM with fused reparameterization (XL/HENC dead -> GI0 overlays them)
    k_gemm_f32<0,1><<<dim3(512, 6), 256, 0, stream>>>(nullptr, Wih0, nullptr, bih0, GI0, 768, 128, mu, lv, eps);
    // reset scan0 exchange tags
    hipMemsetAsync(XBUF0, 0, 131072, stream);
    // scan layer 0 (4 blocks/batch, tagged-atomic exchange) -> H0S
    k_scan0<<<256, 256, 0, stream>>>(GI0, Whh0, bhh0, ln_g0, ln_b0, H0S, XBUF0);
    // hoist layer-1 ih GEMM: gi1 = Wih1 @ h0 (+bih1), frozen-order (GI0 dead -> GI1 overlays)
    k_gi1<<<dim3(256, 2), 256, 0, stream>>>(H0S, Wih1, bih1, GI1);
    // decoder with fused reparameterization (H0S dead after k_gi1 -> overwrite xrec)
    k_gemm_f32<3,1><<<dim3(512, 2), 256, 0, stream>>>(nullptr, Wdec, nullptr, bdec, xrec, 256, 128, mu, lv, eps);
    // scan layer 1: single block per batch, LDS-only sync
    k_scan1<<<64, 512, 0, stream>>>(GI1, Whh1, bhh1, ln_g1, ln_b1, fc_W, fc_b, v_out);
}